// Round 9
// baseline (110.817 us; speedup 1.0000x reference)
//
#include <hip/hip_runtime.h>

#define T_GT 64
#define KP 4            // priors per thread, strided by TPB within the block
#define TPB 256
#define NB 128          // screen bins per axis (1/128 exact pow2)

typedef unsigned int u32;
typedef unsigned long long u64;

// ---------------------------------------------------------------------------
// Round-9: crossbar loop made exec-mask-safe (round-8 post-mortem).
//
// Round-8 failed correctness (absmax 383): __shfl == ds_bpermute, and
// lanes INACTIVE at the instruction contribute undefined data to the
// crossbar. The shfls sat inside the divergent while(mask) loop; lanes
// exhaust masks at different counts, so reads sourcing a finished (inactive)
// lane returned garbage -> corrupted mbest and s_best atomics.
//
// Fix: wave-uniform trip count -- while (__any(mask != 0)) keeps ALL 64
// lanes active until the whole wave is done (same cycle count as the
// divergent loop: both run max-lane-popcount iterations). Per-lane updates
// predicated by live = (mask != 0); mask &= mask-1 is a no-op at 0.
// All shfls execute at full exec -> defined. Epilogue shfls were already
// at reconvergence (full exec) and stay as-is.
// Also: gar recomputed from the 4 shuffled coords with the identical
// __f*_rn ops (bit-exact == s_ga) -- one less LDS-pipe op per iter.
//
// Structure (r8): gt[lane] in registers per wave; screen tables built by
// __ballot (lane == t); NB=128; inter>0 gate; full-exec k body with
// pe=min(p,P-1) (dup-of-P-1 ties harmlessly, r1-r6 invariant); only
// output stores guarded by p<P.
//
// Screen (r5-r7, verified): SUPERSET of inter>0 suffices: phase-2 yields
// q=+0.0 for non-overlapping candidates and the packings (q<<32)|(63-t) /
// (q<<32)|(~p) make q=0 lose to the defaults exactly. Tables:
// T0[i]={t: gb.z > i/NB}, T1[i]={t: gb.x < (i+1)/NB}, T2/T3 same for y.
// floor(px*NB) exact (pow2 mul + _rd) -> superset by construction.
//
// Two-kernel split (r3): main uses plain cached stores; finisher applies
// matches[best_prior[t]]=t. Kernel-boundary ordering = visibility.
//
// Invariants (r1-r7):
//  match: pack (q<<32)|(63-t) max (63-t: first-index tie-break);
//  best_prior: per-wave LDS atomicMax (q<<32)|(0xFFFFFFFF - p) per t;
//  defaults == numpy argmax over implicit all-zero rows/cols.
// ---------------------------------------------------------------------------
__global__ void __launch_bounds__(256)
match_main(const float4* __restrict__ priors,
           const float4* __restrict__ gt_boxes,
           const int* __restrict__ gt_labels,
           u64* __restrict__ part,        // (B, NG, 64) block partials
           float* __restrict__ out_loc,   // (B, P, 4)
           float* __restrict__ out_lbl,   // (B, P) as float
           int P, int NG) {
    __shared__ u64 s_best[4][T_GT];
    __shared__ u64 s_tab[4][NB];

    const int tid  = threadIdx.x;
    const int lane = tid & 63;
    const int wv   = tid >> 6;
    const int b    = blockIdx.y;
    const int pbase = blockIdx.x * (TPB * KP);

    // every wave holds gt[lane] in registers (shfl/ballot source)
    const float4 gb  = gt_boxes[b * T_GT + lane];
    const int    g_lb = gt_labels[b * T_GT + lane];

    s_best[wv][lane] = (u64)0xFFFFFFFFu;   // {q=+0.0, p=0} default

    // ---- ballot table build: wave = axis, bit of ballot = lane = t ----
    if (wv == 0) {
        #pragma unroll 8
        for (int bin = 0; bin < NB; ++bin) {
            const u64 m = __ballot(gb.z > (float)bin * (1.0f / NB));
            if (lane == 0) s_tab[0][bin] = m;
        }
    } else if (wv == 1) {
        #pragma unroll 8
        for (int bin = 0; bin < NB; ++bin) {
            const u64 m = __ballot(gb.x < (float)(bin + 1) * (1.0f / NB));
            if (lane == 0) s_tab[1][bin] = m;
        }
    } else if (wv == 2) {
        #pragma unroll 8
        for (int bin = 0; bin < NB; ++bin) {
            const u64 m = __ballot(gb.w > (float)bin * (1.0f / NB));
            if (lane == 0) s_tab[2][bin] = m;
        }
    } else {
        #pragma unroll 8
        for (int bin = 0; bin < NB; ++bin) {
            const u64 m = __ballot(gb.y < (float)(bin + 1) * (1.0f / NB));
            if (lane == 0) s_tab[3][bin] = m;
        }
    }
    __syncthreads();

    // ---- per-prior fused loop: setup -> screen -> phase2 -> epilogue ----
    #pragma unroll
    for (int k = 0; k < KP; ++k) {
        const int p  = pbase + k * TPB + tid;   // strided: coalesced LD/ST
        const int pe = min(p, P - 1);           // clamp: dup of P-1 harmless

        const float4 pr = priors[pe];
        const float px0 = __fsub_rn(pr.x, __fmul_rn(0.5f, pr.z));
        const float py0 = __fsub_rn(pr.y, __fmul_rn(0.5f, pr.w));
        const float px1 = __fadd_rn(pr.x, __fmul_rn(0.5f, pr.z));
        const float py1 = __fadd_rn(pr.y, __fmul_rn(0.5f, pr.w));
        const float pa  = __fmul_rn(__fsub_rn(px1, px0), __fsub_rn(py1, py0));

        // guard-free bins: px*NB exact (pow2), _rd == floor
        const int bx0 = min(max(__float2int_rd(px0 * (float)NB), 0), NB - 1);
        const int bx1 = min(max(__float2int_rd(px1 * (float)NB), 0), NB - 1);
        const int by0 = min(max(__float2int_rd(py0 * (float)NB), 0), NB - 1);
        const int by1 = min(max(__float2int_rd(py1 * (float)NB), 0), NB - 1);

        u64 mask = s_tab[0][bx0] & s_tab[1][bx1] &
                   s_tab[2][by0] & s_tab[3][by1];   // superset of inter>0

        u64 mbest = 63u;                  // {q=0, rt=63} == t 0
        // wave-uniform trip count: ALL lanes stay active -> shfls defined.
        while (__any(mask != 0)) {
            const bool live = (mask != 0);
            const int  t = live ? (int)__builtin_ctzll(mask) : 0;
            mask &= mask - 1;             // 0 stays 0
            // crossbar fetch of gt[t] at FULL exec -- defined, no conflicts
            const float gx0 = __shfl(gb.x, t, 64);
            const float gy0 = __shfl(gb.y, t, 64);
            const float gx1 = __shfl(gb.z, t, 64);
            const float gy1 = __shfl(gb.w, t, 64);
            // bit-exact recompute of gt area (same __f*_rn ops as s_ga)
            const float gar = __fmul_rn(__fsub_rn(gx1, gx0),
                                        __fsub_rn(gy1, gy0));

            const float wx = fmaxf(__fsub_rn(fminf(gx1, px1),
                                             fmaxf(gx0, px0)), 0.0f);
            const float wy = fmaxf(__fsub_rn(fminf(gy1, py1),
                                             fmaxf(gy0, py0)), 0.0f);
            const float inter = __fmul_rn(wx, wy);
            if (live && inter > 0.0f) {   // q=0 candidates can never win
                const float uni = __fsub_rn(__fadd_rn(gar, pa), inter);
                const float q = __fdiv_rn(inter, uni);  // IEEE: argmax order
                const u64 qh = (u64)__float_as_uint(q) << 32;
                const u64 mp = qh | (u32)(63 - t);
                if (mp > mbest) mbest = mp;
                atomicMax(&s_best[wv][t], qh | (u64)(0xFFFFFFFFu - (u32)pe));
            }
        }

        // epilogue (full exec reconvergence; only stores guarded)
        const int   t_best = 63 - (int)(mbest & 63u);
        const float q_best = __uint_as_float((u32)(mbest >> 32));
        const float mx0 = __shfl(gb.x, t_best, 64);
        const float my0 = __shfl(gb.y, t_best, 64);
        const float mx1 = __shfl(gb.z, t_best, 64);
        const float my1 = __shfl(gb.w, t_best, 64);
        const int   tl  = __shfl(g_lb, t_best, 64);
        const int   lbl = (q_best < 0.5f) ? 0 : tl;

        const float bcx = (mx0 + mx1) * 0.5f;
        const float bcy = (my0 + my1) * 0.5f;
        const float bw  = mx1 - mx0;
        const float bh  = my1 - my0;

        const float lx = __fdividef(bcx - pr.x, 0.1f * pr.z);
        const float ly = __fdividef(bcy - pr.y, 0.1f * pr.w);
        const float lz = __logf(__fdividef(bw, pr.z)) * 5.0f;
        const float lw = __logf(__fdividef(bh, pr.w)) * 5.0f;

        if (p < P) {
            float4* rowp = (float4*)(out_loc + ((size_t)b * P + p) * 4);
            *rowp = make_float4(lx, ly, lz, lw);
            out_lbl[(size_t)b * P + p] = (float)lbl;
        }
    }

    __syncthreads();
    if (tid < T_GT) {
        u64 m = s_best[0][tid];
        #pragma unroll
        for (int w = 1; w < 4; ++w) {
            const u64 v = s_best[w][tid];
            if (v > m) m = v;
        }
        part[((size_t)b * NG + blockIdx.x) * T_GT + tid] = m;   // plain store
    }
}

// ---------------------------------------------------------------------------
// Finisher: one block per image. Reduce NG partials per t, apply
// matches[best_prior[t]] = t (ascending-scan dedupe = numpy last-wins).
// ---------------------------------------------------------------------------
__global__ void __launch_bounds__(256)
match_fin(const float4* __restrict__ priors,
          const float4* __restrict__ gt_boxes,
          const int* __restrict__ gt_labels,
          const u64* __restrict__ part,
          float* __restrict__ out_loc,
          float* __restrict__ out_lbl,
          int P, int NG) {
    __shared__ float4 s_gt[T_GT];
    __shared__ int    s_lbl[T_GT];
    __shared__ u64    s_best[4][T_GT];
    __shared__ u32    s_p[T_GT];

    const int tid = threadIdx.x;
    const int b   = blockIdx.x;
    const int t   = tid & 63;
    const int w   = tid >> 6;

    if (tid < T_GT) {
        s_gt[tid]  = gt_boxes[b * T_GT + tid];
        s_lbl[tid] = gt_labels[b * T_GT + tid];
    }

    const size_t base = (size_t)b * NG * T_GT + t;
    u64 m = 0;
    int g = w;
    for (; g + 12 < NG; g += 16) {      // 4 independent loads in flight
        const u64 a0 = part[base + (size_t)g * T_GT];
        const u64 a1 = part[base + (size_t)(g + 4) * T_GT];
        const u64 a2 = part[base + (size_t)(g + 8) * T_GT];
        const u64 a3 = part[base + (size_t)(g + 12) * T_GT];
        u64 x = a0 > a1 ? a0 : a1;
        const u64 y = a2 > a3 ? a2 : a3;
        if (y > x) x = y;
        if (x > m) m = x;
    }
    for (; g < NG; g += 4) {
        const u64 v = part[base + (size_t)g * T_GT];
        if (v > m) m = v;
    }
    s_best[w][t] = m;
    __syncthreads();
    if (tid < T_GT) {
        m = s_best[0][t];
        #pragma unroll
        for (int i = 1; i < 4; ++i) {
            const u64 v = s_best[i][t];
            if (v > m) m = v;
        }
        s_p[t] = 0xFFFFFFFFu - (u32)(m & 0xFFFFFFFFull);
    }
    __syncthreads();
    if (tid >= T_GT) return;

    // matches[best_prior] = arange(T): numpy last-wins on duplicates
    const u32 p = s_p[tid];
    for (int u = tid + 1; u < T_GT; ++u)
        if (s_p[u] == p) return;

    const float4 pr = priors[p];
    const float4 mb = s_gt[tid];
    const float  bcx = (mb.x + mb.z) * 0.5f;
    const float  bcy = (mb.y + mb.w) * 0.5f;
    const float  bw  = mb.z - mb.x;
    const float  bh  = mb.w - mb.y;

    const float lx = __fdividef(bcx - pr.x, 0.1f * pr.z);
    const float ly = __fdividef(bcy - pr.y, 0.1f * pr.w);
    const float lz = __logf(__fdividef(bw, pr.z)) * 5.0f;
    const float lw = __logf(__fdividef(bh, pr.w)) * 5.0f;

    float4* rowp = (float4*)(out_loc + ((size_t)b * P + p) * 4);
    *rowp = make_float4(lx, ly, lz, lw);
    out_lbl[(size_t)b * P + p] = (float)s_lbl[tid];
}

extern "C" void kernel_launch(void* const* d_in, const int* in_sizes, int n_in,
                              void* d_out, int out_size, void* d_ws, size_t ws_size,
                              hipStream_t stream) {
    const float4* priors    = (const float4*)d_in[0];   // (P, 4) f32
    const float4* gt_boxes  = (const float4*)d_in[1];   // (B, T, 4) f32
    const int*    gt_labels = (const int*)d_in[2];      // (B, T) i32

    const int P = in_sizes[0] / 4;
    const int B = in_sizes[2] / T_GT;

    float* out_loc = (float*)d_out;
    float* out_lbl = out_loc + (size_t)B * P * 4;

    const int NG = (P + TPB * KP - 1) / (TPB * KP);   // blocks per image (98)
    u64* part = (u64*)d_ws;                            // (B, NG, 64) u64

    dim3 g(NG, B);
    match_main<<<g, TPB, 0, stream>>>(priors, gt_boxes, gt_labels, part,
                                      out_loc, out_lbl, P, NG);
    match_fin<<<dim3(B), TPB, 0, stream>>>(priors, gt_boxes, gt_labels, part,
                                           out_loc, out_lbl, P, NG);
}

// Round 10
// 105.296 us; speedup vs baseline: 1.0524x; 1.0524x over previous
//
#include <hip/hip_runtime.h>

#define T_GT 64
#define KP 4            // priors per thread, strided by TPB within the block
#define TPB 256
#define NB 64           // screen bins per axis (1/64 exact pow2)

typedef unsigned int u32;
typedef unsigned long long u64;

// ---------------------------------------------------------------------------
// Round-10: r7 skeleton + SoA gt in LDS + ballot tables + inter>0 gate.
//
// Round-9 post-mortem: shfl loop REGRESSED (44 vs ~34us): 4 ds_bpermute/iter
// is MORE LDS-pipe work than 2 reads; conflicts rose 1.09M->1.9M. Also
// VALUBusy is inflated ~2x (gfx94x 4-cyc formula vs CDNA4 SIMD-32 2-cyc)
// -> VALU is NOT saturated; the cost is LDS traffic + dep stalls.
//
// This round attacks r7's measured LDS term:
//  (1) SoA s_gx0/s_gy0/s_gx1/s_gy1[64]: divergent b32 reads spread over 32
//      banks (~4-way) vs b128 at t*16 hitting 8 bank-groups (~13-way) --
//      the 1.09M conflict counter.
//  (2) s_ga dropped: area recomputed from the 4 loaded coords, identical
//      __f*_rn ops == bit-exact (trades 1 LDS op for 3 VALU).
//  (3) Ballot-built screen tables (r9, proven): gt in regs per wave, no
//      LDS reads in build; wave 0 seeds SoA + labels.
//  (4) inter>0 gate (r8/r9, proven): screen FPs skip div+atomic; q=0
//      candidates provably lose to all defaults.
//
// Screen (r5-r7, verified): SUPERSET of inter>0 suffices. Tables:
// T0[i]={t: gb.z > i/NB}, T1[i]={t: gb.x < (i+1)/NB}, T2/T3 same for y.
// floor(px*NB) exact (pow2 mul + _rd) -> superset by construction.
//
// Two-kernel split (r3): main uses plain cached stores; finisher applies
// matches[best_prior[t]]=t. Kernel-boundary ordering = visibility.
//
// Invariants (r1-r9):
//  match: pack (q<<32)|(63-t) max (63-t: first-index tie-break);
//  best_prior: per-wave LDS atomicMax (q<<32)|(0xFFFFFFFF - p) per t;
//  defaults == numpy argmax over implicit all-zero rows/cols.
//  NO shfl inside the divergent loop (r8 lesson: inactive lanes feed the
//  crossbar garbage); LDS reads are exec-safe there.
// ---------------------------------------------------------------------------
__global__ void __launch_bounds__(256)
match_main(const float4* __restrict__ priors,
           const float4* __restrict__ gt_boxes,
           const int* __restrict__ gt_labels,
           u64* __restrict__ part,        // (B, NG, 64) block partials
           float* __restrict__ out_loc,   // (B, P, 4)
           float* __restrict__ out_lbl,   // (B, P) as float
           int P, int NG) {
    __shared__ float s_gx0[T_GT], s_gy0[T_GT], s_gx1[T_GT], s_gy1[T_GT];
    __shared__ int   s_lbl[T_GT];
    __shared__ u64   s_best[4][T_GT];
    __shared__ u64   s_tab[4][NB];

    const int tid  = threadIdx.x;
    const int lane = tid & 63;
    const int wv   = tid >> 6;
    const int b    = blockIdx.y;
    const int pbase = blockIdx.x * (TPB * KP);

    // every wave holds gt[lane] in registers (ballot source)
    const float4 gb = gt_boxes[b * T_GT + lane];

    if (wv == 0) {                      // wave 0 seeds SoA gt + labels
        s_gx0[lane] = gb.x;
        s_gy0[lane] = gb.y;
        s_gx1[lane] = gb.z;
        s_gy1[lane] = gb.w;
        s_lbl[lane] = gt_labels[b * T_GT + lane];
    }
    s_best[wv][lane] = (u64)0xFFFFFFFFu;   // {q=+0.0, p=0} default

    // ---- ballot table build: wave = axis, bit of ballot = lane = t ----
    if (wv == 0) {
        #pragma unroll 8
        for (int bin = 0; bin < NB; ++bin) {
            const u64 m = __ballot(gb.z > (float)bin * (1.0f / NB));
            if (lane == 0) s_tab[0][bin] = m;
        }
    } else if (wv == 1) {
        #pragma unroll 8
        for (int bin = 0; bin < NB; ++bin) {
            const u64 m = __ballot(gb.x < (float)(bin + 1) * (1.0f / NB));
            if (lane == 0) s_tab[1][bin] = m;
        }
    } else if (wv == 2) {
        #pragma unroll 8
        for (int bin = 0; bin < NB; ++bin) {
            const u64 m = __ballot(gb.w > (float)bin * (1.0f / NB));
            if (lane == 0) s_tab[2][bin] = m;
        }
    } else {
        #pragma unroll 8
        for (int bin = 0; bin < NB; ++bin) {
            const u64 m = __ballot(gb.y < (float)(bin + 1) * (1.0f / NB));
            if (lane == 0) s_tab[3][bin] = m;
        }
    }
    __syncthreads();

    // ---- per-prior fused loop: setup -> screen -> phase2 -> epilogue ----
    #pragma unroll
    for (int k = 0; k < KP; ++k) {
        const int p = pbase + k * TPB + tid;    // strided: coalesced LD/ST
        if (p < P) {
            const float4 pr = priors[p];
            const float px0 = __fsub_rn(pr.x, __fmul_rn(0.5f, pr.z));
            const float py0 = __fsub_rn(pr.y, __fmul_rn(0.5f, pr.w));
            const float px1 = __fadd_rn(pr.x, __fmul_rn(0.5f, pr.z));
            const float py1 = __fadd_rn(pr.y, __fmul_rn(0.5f, pr.w));
            const float pa  = __fmul_rn(__fsub_rn(px1, px0),
                                        __fsub_rn(py1, py0));

            // guard-free bins: px*NB exact (pow2), _rd == floor
            const int bx0 = min(max(__float2int_rd(px0 * (float)NB), 0), NB - 1);
            const int bx1 = min(max(__float2int_rd(px1 * (float)NB), 0), NB - 1);
            const int by0 = min(max(__float2int_rd(py0 * (float)NB), 0), NB - 1);
            const int by1 = min(max(__float2int_rd(py1 * (float)NB), 0), NB - 1);

            u64 mask = s_tab[0][bx0] & s_tab[1][bx1] &
                       s_tab[2][by0] & s_tab[3][by1];   // superset of inter>0

            u64 mbest = 63u;                  // {q=0, rt=63} == t 0
            while (mask) {                    // ascending t per lane
                const int t = (int)__builtin_ctzll(mask);
                mask &= mask - 1;
                // SoA b32 reads: spread over 32 banks (vs b128 8 groups)
                const float gx0 = s_gx0[t];
                const float gy0 = s_gy0[t];
                const float gx1 = s_gx1[t];
                const float gy1 = s_gy1[t];
                // bit-exact recompute of gt area (same ops as old s_ga)
                const float gar = __fmul_rn(__fsub_rn(gx1, gx0),
                                            __fsub_rn(gy1, gy0));

                const float wx = fmaxf(__fsub_rn(fminf(gx1, px1),
                                                 fmaxf(gx0, px0)), 0.0f);
                const float wy = fmaxf(__fsub_rn(fminf(gy1, py1),
                                                 fmaxf(gy0, py0)), 0.0f);
                const float inter = __fmul_rn(wx, wy);
                if (inter > 0.0f) {           // screen FPs skip div+atomic
                    const float uni = __fsub_rn(__fadd_rn(gar, pa), inter);
                    const float q = __fdiv_rn(inter, uni);  // IEEE: argmax
                    const u64 qh = (u64)__float_as_uint(q) << 32;
                    const u64 mp = qh | (u32)(63 - t);
                    if (mp > mbest) mbest = mp;
                    atomicMax(&s_best[wv][t],
                              qh | (u64)(0xFFFFFFFFu - (u32)p));
                }
            }

            // epilogue: cheap native math (not in argmax path)
            const int   t_best = 63 - (int)(mbest & 63u);
            const float q_best = __uint_as_float((u32)(mbest >> 32));
            const int   lbl = (q_best < 0.5f) ? 0 : s_lbl[t_best];

            const float mx0 = s_gx0[t_best];
            const float my0 = s_gy0[t_best];
            const float mx1 = s_gx1[t_best];
            const float my1 = s_gy1[t_best];

            const float bcx = (mx0 + mx1) * 0.5f;
            const float bcy = (my0 + my1) * 0.5f;
            const float bw  = mx1 - mx0;
            const float bh  = my1 - my0;

            const float lx = __fdividef(bcx - pr.x, 0.1f * pr.z);
            const float ly = __fdividef(bcy - pr.y, 0.1f * pr.w);
            const float lz = __logf(__fdividef(bw, pr.z)) * 5.0f;
            const float lw = __logf(__fdividef(bh, pr.w)) * 5.0f;

            float4* rowp = (float4*)(out_loc + ((size_t)b * P + p) * 4);
            *rowp = make_float4(lx, ly, lz, lw);
            out_lbl[(size_t)b * P + p] = (float)lbl;
        }
    }

    __syncthreads();
    if (tid < T_GT) {
        u64 m = s_best[0][tid];
        #pragma unroll
        for (int w = 1; w < 4; ++w) {
            const u64 v = s_best[w][tid];
            if (v > m) m = v;
        }
        part[((size_t)b * NG + blockIdx.x) * T_GT + tid] = m;   // plain store
    }
}

// ---------------------------------------------------------------------------
// Finisher: one block per image. Reduce NG partials per t, apply
// matches[best_prior[t]] = t (ascending-scan dedupe = numpy last-wins).
// ---------------------------------------------------------------------------
__global__ void __launch_bounds__(256)
match_fin(const float4* __restrict__ priors,
          const float4* __restrict__ gt_boxes,
          const int* __restrict__ gt_labels,
          const u64* __restrict__ part,
          float* __restrict__ out_loc,
          float* __restrict__ out_lbl,
          int P, int NG) {
    __shared__ float4 s_gt[T_GT];
    __shared__ int    s_lbl[T_GT];
    __shared__ u64    s_best[4][T_GT];
    __shared__ u32    s_p[T_GT];

    const int tid = threadIdx.x;
    const int b   = blockIdx.x;
    const int t   = tid & 63;
    const int w   = tid >> 6;

    if (tid < T_GT) {
        s_gt[tid]  = gt_boxes[b * T_GT + tid];
        s_lbl[tid] = gt_labels[b * T_GT + tid];
    }

    const size_t base = (size_t)b * NG * T_GT + t;
    u64 m = 0;
    int g = w;
    for (; g + 12 < NG; g += 16) {      // 4 independent loads in flight
        const u64 a0 = part[base + (size_t)g * T_GT];
        const u64 a1 = part[base + (size_t)(g + 4) * T_GT];
        const u64 a2 = part[base + (size_t)(g + 8) * T_GT];
        const u64 a3 = part[base + (size_t)(g + 12) * T_GT];
        u64 x = a0 > a1 ? a0 : a1;
        const u64 y = a2 > a3 ? a2 : a3;
        if (y > x) x = y;
        if (x > m) m = x;
    }
    for (; g < NG; g += 4) {
        const u64 v = part[base + (size_t)g * T_GT];
        if (v > m) m = v;
    }
    s_best[w][t] = m;
    __syncthreads();
    if (tid < T_GT) {
        m = s_best[0][t];
        #pragma unroll
        for (int i = 1; i < 4; ++i) {
            const u64 v = s_best[i][t];
            if (v > m) m = v;
        }
        s_p[t] = 0xFFFFFFFFu - (u32)(m & 0xFFFFFFFFull);
    }
    __syncthreads();
    if (tid >= T_GT) return;

    // matches[best_prior] = arange(T): numpy last-wins on duplicates
    const u32 p = s_p[tid];
    for (int u = tid + 1; u < T_GT; ++u)
        if (s_p[u] == p) return;

    const float4 pr = priors[p];
    const float4 mb = s_gt[tid];
    const float  bcx = (mb.x + mb.z) * 0.5f;
    const float  bcy = (mb.y + mb.w) * 0.5f;
    const float  bw  = mb.z - mb.x;
    const float  bh  = mb.w - mb.y;

    const float lx = __fdividef(bcx - pr.x, 0.1f * pr.z);
    const float ly = __fdividef(bcy - pr.y, 0.1f * pr.w);
    const float lz = __logf(__fdividef(bw, pr.z)) * 5.0f;
    const float lw = __logf(__fdividef(bh, pr.w)) * 5.0f;

    float4* rowp = (float4*)(out_loc + ((size_t)b * P + p) * 4);
    *rowp = make_float4(lx, ly, lz, lw);
    out_lbl[(size_t)b * P + p] = (float)s_lbl[tid];
}

extern "C" void kernel_launch(void* const* d_in, const int* in_sizes, int n_in,
                              void* d_out, int out_size, void* d_ws, size_t ws_size,
                              hipStream_t stream) {
    const float4* priors    = (const float4*)d_in[0];   // (P, 4) f32
    const float4* gt_boxes  = (const float4*)d_in[1];   // (B, T, 4) f32
    const int*    gt_labels = (const int*)d_in[2];      // (B, T) i32

    const int P = in_sizes[0] / 4;
    const int B = in_sizes[2] / T_GT;

    float* out_loc = (float*)d_out;
    float* out_lbl = out_loc + (size_t)B * P * 4;

    const int NG = (P + TPB * KP - 1) / (TPB * KP);   // blocks per image (98)
    u64* part = (u64*)d_ws;                            // (B, NG, 64) u64

    dim3 g(NG, B);
    match_main<<<g, TPB, 0, stream>>>(priors, gt_boxes, gt_labels, part,
                                      out_loc, out_lbl, P, NG);
    match_fin<<<dim3(B), TPB, 0, stream>>>(priors, gt_boxes, gt_labels, part,
                                           out_loc, out_lbl, P, NG);
}

// Round 11
// 104.135 us; speedup vs baseline: 1.0642x; 1.0111x over previous
//
#include <hip/hip_runtime.h>

#define T_GT 64
#define KP 4            // priors per thread, strided by TPB within the block
#define TPB 256
#define NB 64           // screen bins per axis (1/64 exact pow2)

typedef unsigned int u32;
typedef unsigned long long u64;

// ---------------------------------------------------------------------------
// Round-11: r7 skeleton + 2-deep LDS pipeline + hoisted prior loads.
//
// Rounds 8-10 post-mortem: kernel is LATENCY-bound in the candidate loop,
// not throughput-bound: throughput floor ~10-12us/CU vs ~34 measured;
// VALU cuts (r4), conflict cuts (r10) and crossbar (r9, regressed) all
// failed to move time. Dep chain per iteration: ctz -> ds_read_b128
// (~40cyc) -> ~25cyc VALU -> div -> atomic, at only ~6 waves/SIMD.
//
// Fixes (latency hiding only; work unchanged):
//  (1) 2-deep pipeline: issue s_gt[t_{i+1}] before processing t_i. The
//      compiler's fine-grained lgkmcnt leaves one b128 in flight under
//      the previous iteration's compute. Prefetch uses t=0 when a lane's
//      mask empties -- LDS reads are exec-safe (r8 lesson: shfl is NOT).
//  (2) All KP priors[] loads hoisted above the k-loop (unconditional,
//      pe=min(p,P-1) clamp -- r8-r10 proven invariant; only stores are
//      guarded): 4 independent VMEM issues, one wait, vs 4 serial
//      ~200cyc exposures.
//  (3) Kept from r9/r10 (proven, bit-exact): gt area recomputed from the
//      4 loaded coords (identical __f*_rn ops) -- no s_ga read; ballot
//      table build (no LDS in build).
//
// Screen (r5-r7, verified): SUPERSET of inter>0 suffices: phase-2 yields
// q=+0.0 for non-overlapping candidates and the packings (q<<32)|(63-t) /
// (q<<32)|(~p) make q=0 lose to the defaults exactly. Tables:
// T0[i]={t: gb.z > i/NB}, T1[i]={t: gb.x < (i+1)/NB}, T2/T3 same for y.
// floor(px*NB) exact (pow2 mul + _rd) -> superset by construction.
//
// Two-kernel split (r3): main uses plain cached stores; finisher applies
// matches[best_prior[t]]=t. Kernel-boundary ordering = visibility.
//
// Invariants (r1-r10):
//  match: pack (q<<32)|(63-t) max (63-t: first-index tie-break);
//  best_prior: per-wave LDS atomicMax (q<<32)|(0xFFFFFFFF - p) per t;
//  defaults == numpy argmax over implicit all-zero rows/cols.
//  Empty-mask lanes: mbest=63 -> t_best=0, q=0 -> lbl=0 (= numpy default).
// ---------------------------------------------------------------------------
__global__ void __launch_bounds__(256)
match_main(const float4* __restrict__ priors,
           const float4* __restrict__ gt_boxes,
           const int* __restrict__ gt_labels,
           u64* __restrict__ part,        // (B, NG, 64) block partials
           float* __restrict__ out_loc,   // (B, P, 4)
           float* __restrict__ out_lbl,   // (B, P) as float
           int P, int NG) {
    __shared__ float4 s_gt[T_GT];
    __shared__ int    s_lbl[T_GT];
    __shared__ u64    s_best[4][T_GT];
    __shared__ u64    s_tab[4][NB];

    const int tid  = threadIdx.x;
    const int lane = tid & 63;
    const int wv   = tid >> 6;
    const int b    = blockIdx.y;
    const int pbase = blockIdx.x * (TPB * KP);

    // every wave holds gt[lane] in registers (ballot source)
    const float4 gb = gt_boxes[b * T_GT + lane];

    if (wv == 0) {                      // wave 0 seeds s_gt + labels
        s_gt[lane]  = gb;
        s_lbl[lane] = gt_labels[b * T_GT + lane];
    }
    s_best[wv][lane] = (u64)0xFFFFFFFFu;   // {q=+0.0, p=0} default

    // ---- ballot table build: wave = axis, bit of ballot = lane = t ----
    if (wv == 0) {
        #pragma unroll 8
        for (int bin = 0; bin < NB; ++bin) {
            const u64 m = __ballot(gb.z > (float)bin * (1.0f / NB));
            if (lane == 0) s_tab[0][bin] = m;
        }
    } else if (wv == 1) {
        #pragma unroll 8
        for (int bin = 0; bin < NB; ++bin) {
            const u64 m = __ballot(gb.x < (float)(bin + 1) * (1.0f / NB));
            if (lane == 0) s_tab[1][bin] = m;
        }
    } else if (wv == 2) {
        #pragma unroll 8
        for (int bin = 0; bin < NB; ++bin) {
            const u64 m = __ballot(gb.w > (float)bin * (1.0f / NB));
            if (lane == 0) s_tab[2][bin] = m;
        }
    } else {
        #pragma unroll 8
        for (int bin = 0; bin < NB; ++bin) {
            const u64 m = __ballot(gb.y < (float)(bin + 1) * (1.0f / NB));
            if (lane == 0) s_tab[3][bin] = m;
        }
    }

    // hoisted prior loads: 4 independent VMEM issues, one wait
    float4 prk[KP];
    #pragma unroll
    for (int k = 0; k < KP; ++k)
        prk[k] = priors[min(pbase + k * TPB + tid, P - 1)];

    __syncthreads();

    // ---- per-prior fused loop: setup -> screen -> phase2 -> epilogue ----
    #pragma unroll
    for (int k = 0; k < KP; ++k) {
        const int p  = pbase + k * TPB + tid;   // strided: coalesced ST
        const float4 pr = prk[k];
        const float px0 = __fsub_rn(pr.x, __fmul_rn(0.5f, pr.z));
        const float py0 = __fsub_rn(pr.y, __fmul_rn(0.5f, pr.w));
        const float px1 = __fadd_rn(pr.x, __fmul_rn(0.5f, pr.z));
        const float py1 = __fadd_rn(pr.y, __fmul_rn(0.5f, pr.w));
        const float pa  = __fmul_rn(__fsub_rn(px1, px0),
                                    __fsub_rn(py1, py0));

        // guard-free bins: px*NB exact (pow2), _rd == floor
        const int bx0 = min(max(__float2int_rd(px0 * (float)NB), 0), NB - 1);
        const int bx1 = min(max(__float2int_rd(px1 * (float)NB), 0), NB - 1);
        const int by0 = min(max(__float2int_rd(py0 * (float)NB), 0), NB - 1);
        const int by1 = min(max(__float2int_rd(py1 * (float)NB), 0), NB - 1);

        u64 mask = s_tab[0][bx0] & s_tab[1][bx1] &
                   s_tab[2][by0] & s_tab[3][by1];   // superset of inter>0

        u64 mbest = 63u;                  // {q=0, rt=63} == t 0

        // 2-deep pipeline: g0 in flight while previous iteration computes
        bool live = (mask != 0);
        int  t0 = live ? (int)__builtin_ctzll(mask) : 0;
        mask &= mask - 1;
        float4 g0 = s_gt[t0];             // prefetch (exec-safe LDS read)

        while (live) {
            const bool live1 = (mask != 0);
            const int  t1 = live1 ? (int)__builtin_ctzll(mask) : 0;
            mask &= mask - 1;
            const float4 g1 = s_gt[t1];   // issue next before using g0

            // bit-exact recompute of gt area (same __f*_rn ops as s_ga)
            const float gar = __fmul_rn(__fsub_rn(g0.z, g0.x),
                                        __fsub_rn(g0.w, g0.y));
            const float wx = fmaxf(__fsub_rn(fminf(g0.z, px1),
                                             fmaxf(g0.x, px0)), 0.0f);
            const float wy = fmaxf(__fsub_rn(fminf(g0.w, py1),
                                             fmaxf(g0.y, py0)), 0.0f);
            const float inter = __fmul_rn(wx, wy);
            const float uni = __fsub_rn(__fadd_rn(gar, pa), inter);
            const float q = __fdiv_rn(inter, uni);  // IEEE: argmax order
            const u64 qh = (u64)__float_as_uint(q) << 32;
            const u64 mp = qh | (u32)(63 - t0);
            if (mp > mbest) mbest = mp;
            atomicMax(&s_best[wv][t0],
                      qh | (u64)(0xFFFFFFFFu - (u32)min(p, P - 1)));

            g0 = g1; t0 = t1; live = live1;
        }

        // epilogue: cheap native math (not in argmax path)
        const int   t_best = 63 - (int)(mbest & 63u);
        const float q_best = __uint_as_float((u32)(mbest >> 32));
        const int   lbl = (q_best < 0.5f) ? 0 : s_lbl[t_best];

        const float4 mb = s_gt[t_best];
        const float bcx = (mb.x + mb.z) * 0.5f;
        const float bcy = (mb.y + mb.w) * 0.5f;
        const float bw  = mb.z - mb.x;
        const float bh  = mb.w - mb.y;

        const float lx = __fdividef(bcx - pr.x, 0.1f * pr.z);
        const float ly = __fdividef(bcy - pr.y, 0.1f * pr.w);
        const float lz = __logf(__fdividef(bw, pr.z)) * 5.0f;
        const float lw = __logf(__fdividef(bh, pr.w)) * 5.0f;

        if (p < P) {
            float4* rowp = (float4*)(out_loc + ((size_t)b * P + p) * 4);
            *rowp = make_float4(lx, ly, lz, lw);
            out_lbl[(size_t)b * P + p] = (float)lbl;
        }
    }

    __syncthreads();
    if (tid < T_GT) {
        u64 m = s_best[0][tid];
        #pragma unroll
        for (int w = 1; w < 4; ++w) {
            const u64 v = s_best[w][tid];
            if (v > m) m = v;
        }
        part[((size_t)b * NG + blockIdx.x) * T_GT + tid] = m;   // plain store
    }
}

// ---------------------------------------------------------------------------
// Finisher: one block per image. Reduce NG partials per t, apply
// matches[best_prior[t]] = t (ascending-scan dedupe = numpy last-wins).
// ---------------------------------------------------------------------------
__global__ void __launch_bounds__(256)
match_fin(const float4* __restrict__ priors,
          const float4* __restrict__ gt_boxes,
          const int* __restrict__ gt_labels,
          const u64* __restrict__ part,
          float* __restrict__ out_loc,
          float* __restrict__ out_lbl,
          int P, int NG) {
    __shared__ float4 s_gt[T_GT];
    __shared__ int    s_lbl[T_GT];
    __shared__ u64    s_best[4][T_GT];
    __shared__ u32    s_p[T_GT];

    const int tid = threadIdx.x;
    const int b   = blockIdx.x;
    const int t   = tid & 63;
    const int w   = tid >> 6;

    if (tid < T_GT) {
        s_gt[tid]  = gt_boxes[b * T_GT + tid];
        s_lbl[tid] = gt_labels[b * T_GT + tid];
    }

    const size_t base = (size_t)b * NG * T_GT + t;
    u64 m = 0;
    int g = w;
    for (; g + 12 < NG; g += 16) {      // 4 independent loads in flight
        const u64 a0 = part[base + (size_t)g * T_GT];
        const u64 a1 = part[base + (size_t)(g + 4) * T_GT];
        const u64 a2 = part[base + (size_t)(g + 8) * T_GT];
        const u64 a3 = part[base + (size_t)(g + 12) * T_GT];
        u64 x = a0 > a1 ? a0 : a1;
        const u64 y = a2 > a3 ? a2 : a3;
        if (y > x) x = y;
        if (x > m) m = x;
    }
    for (; g < NG; g += 4) {
        const u64 v = part[base + (size_t)g * T_GT];
        if (v > m) m = v;
    }
    s_best[w][t] = m;
    __syncthreads();
    if (tid < T_GT) {
        m = s_best[0][t];
        #pragma unroll
        for (int i = 1; i < 4; ++i) {
            const u64 v = s_best[i][t];
            if (v > m) m = v;
        }
        s_p[t] = 0xFFFFFFFFu - (u32)(m & 0xFFFFFFFFull);
    }
    __syncthreads();
    if (tid >= T_GT) return;

    // matches[best_prior] = arange(T): numpy last-wins on duplicates
    const u32 p = s_p[tid];
    for (int u = tid + 1; u < T_GT; ++u)
        if (s_p[u] == p) return;

    const float4 pr = priors[p];
    const float4 mb = s_gt[tid];
    const float  bcx = (mb.x + mb.z) * 0.5f;
    const float  bcy = (mb.y + mb.w) * 0.5f;
    const float  bw  = mb.z - mb.x;
    const float  bh  = mb.w - mb.y;

    const float lx = __fdividef(bcx - pr.x, 0.1f * pr.z);
    const float ly = __fdividef(bcy - pr.y, 0.1f * pr.w);
    const float lz = __logf(__fdividef(bw, pr.z)) * 5.0f;
    const float lw = __logf(__fdividef(bh, pr.w)) * 5.0f;

    float4* rowp = (float4*)(out_loc + ((size_t)b * P + p) * 4);
    *rowp = make_float4(lx, ly, lz, lw);
    out_lbl[(size_t)b * P + p] = (float)s_lbl[tid];
}

extern "C" void kernel_launch(void* const* d_in, const int* in_sizes, int n_in,
                              void* d_out, int out_size, void* d_ws, size_t ws_size,
                              hipStream_t stream) {
    const float4* priors    = (const float4*)d_in[0];   // (P, 4) f32
    const float4* gt_boxes  = (const float4*)d_in[1];   // (B, T, 4) f32
    const int*    gt_labels = (const int*)d_in[2];      // (B, T) i32

    const int P = in_sizes[0] / 4;
    const int B = in_sizes[2] / T_GT;

    float* out_loc = (float*)d_out;
    float* out_lbl = out_loc + (size_t)B * P * 4;

    const int NG = (P + TPB * KP - 1) / (TPB * KP);   // blocks per image (98)
    u64* part = (u64*)d_ws;                            // (B, NG, 64) u64

    dim3 g(NG, B);
    match_main<<<g, TPB, 0, stream>>>(priors, gt_boxes, gt_labels, part,
                                      out_loc, out_lbl, P, NG);
    match_fin<<<dim3(B), TPB, 0, stream>>>(priors, gt_boxes, gt_labels, part,
                                           out_loc, out_lbl, P, NG);
}